// Round 11
// baseline (126.679 us; speedup 1.0000x reference)
//
#include <hip/hip_runtime.h>
#include <hip/hip_bf16.h>

// BatchTripletLoss on MI355X — round 11: 4-wave blocks, 128x64/wave, 2 blocks/CU.
// Units: 256x128 (bm<32, bn in [2bm,64) -> 1056), same coverage/finalize as R10.
// Block = 256 thr (2M x 2N waves), per-wave 128x64 -> acc 128 AGPR (2 waves/SIMD),
// BK=32 dbuf = 48KB LDS -> 2 blocks/CU. Better LDS reuse: 0.375 frag-reads/MFMA
// (vs R10's 0.5) cuts the binding LDS-traffic wall ~20%; KT split in two
// read/MFMA half-phases so counted lgkmcnt overlaps reads under MFMA.

#define NROWS 8192
#define DIM   1024
#define BTM   256
#define BTN   128
#define BK    32
#define NKT   (DIM / BK)            // 32 K-tiles
#define NUNITS 1056                 // sum_{bm<32} (64 - 2*bm)

constexpr float EPS = 1e-6f;
constexpr float MARGIN = 0.5f;

typedef __attribute__((ext_vector_type(8))) short short8;
typedef __attribute__((ext_vector_type(4))) float f32x4;

__device__ __forceinline__ unsigned short f2bf_rne(float f) {
    unsigned u = __float_as_uint(f);
    u += 0x7fffu + ((u >> 16) & 1u);
    return (unsigned short)(u >> 16);
}

// ---------------- kernel 1: per-row stats + bf16 conversion ----------------
__global__ void prep_kernel(const float* __restrict__ X, const float* __restrict__ P,
                            unsigned short* __restrict__ Xb,
                            float* __restrict__ cj, float* __restrict__ basei,
                            float* __restrict__ posd, int* __restrict__ valid)
{
    const int tid  = threadIdx.x;
    const int w    = tid >> 6;
    const int lane = tid & 63;
    const int row  = blockIdx.x * 4 + w;
    const float* xr = X + (size_t)row * DIM;

    float sq = 0.f, sm = 0.f, pd = 0.f;
    bool eq = true;
    #pragma unroll
    for (int it = 0; it < 4; ++it) {
        const int idx = it * 256 + lane * 4;
        const float4 x = *(const float4*)(xr + idx);
        const float4 p = *(const float4*)(P + idx);
        sq += x.x*x.x + x.y*x.y + x.z*x.z + x.w*x.w;
        sm += x.x + x.y + x.z + x.w;
        const float d0 = x.x - p.x + EPS, d1 = x.y - p.y + EPS;
        const float d2 = x.z - p.z + EPS, d3 = x.w - p.w + EPS;
        pd += d0*d0 + d1*d1 + d2*d2 + d3*d3;
        eq = eq && (x.x == p.x) && (x.y == p.y) && (x.z == p.z) && (x.w == p.w);
        ushort4 b;
        b.x = f2bf_rne(x.x); b.y = f2bf_rne(x.y); b.z = f2bf_rne(x.z); b.w = f2bf_rne(x.w);
        *(ushort4*)(Xb + (size_t)row * DIM + idx) = b;
    }
    #pragma unroll
    for (int off = 32; off >= 1; off >>= 1) {
        sq += __shfl_xor(sq, off);
        sm += __shfl_xor(sm, off);
        pd += __shfl_xor(pd, off);
    }
    const bool alleq = __all(eq);
    if (lane == 0) {
        cj[row]    = sq - 2.f * EPS * sm;
        basei[row] = sq + 2.f * EPS * sm + (float)DIM * EPS * EPS;
        posd[row]  = sqrtf(pd);
        valid[row] = alleq ? 0 : 1;
    }
}

// ---------------- kernel 2: co-resident symmetric GEMM + row/col max ----------------
// LDS per buf: A = 256x32 = 1024 chunks of 16B (16KB), B = 128x32 = 512 chunks (8KB).
// Swizzle: logical (r,c) chunk at phys p = r*4 + (c ^ ((r>>1)&3)); gload_lds writes
// phys-linear, source pre-permuted (thread q -> row q>>2, K-chunk (q&3)^((q>>3)&3)).
// Frag reads: cx = lk ^ ((l15>>1)&3) -> conflict-free (verified R10: 0 conflicts).
__global__ __launch_bounds__(256, 2) void gemm_max_kernel(
        const unsigned short* __restrict__ Xb,
        const float* __restrict__ cj,
        float* __restrict__ partmax)
{
    __shared__ alignas(16) unsigned short lds[2][1536 * 8];   // [buf][A:0..1023 | B:1024..1535 chunks]

    const int tid  = threadIdx.x;
    const int lane = tid & 63;
    const int wid  = tid >> 6;        // 0..3
    const int wm   = wid >> 1;        // 0..1  (128-row half)
    const int wn   = wid & 1;         // 0..1  (64-col half)
    const int l15  = lane & 15;
    const int lk   = lane >> 4;       // 0..3
    const int cx   = lk ^ ((l15 >> 1) & 3);

    // XCD-chunked bijective unit decode (1056 = 8 * 132); base(bm) = 65*bm - bm*bm
    const int t0 = (blockIdx.x & 7) * (NUNITS / 8) + (blockIdx.x >> 3);
    int bm = (int)(32.5f - sqrtf(1056.25f - (float)t0));
    if (bm < 0) bm = 0;
    if (bm > 31) bm = 31;
    while (bm > 0 && 65 * bm - bm * bm > t0) --bm;
    while (65 * (bm + 1) - (bm + 1) * (bm + 1) <= t0) ++bm;
    const int bn = 2 * bm + (t0 - (65 * bm - bm * bm));
    const int Mbase = bm * BTM, Nbase = bn * BTN;

    f32x4 acc[8][4];
    #pragma unroll
    for (int m = 0; m < 8; ++m)
        #pragma unroll
        for (int n = 0; n < 4; ++n)
            acc[m][n] = (f32x4){0.f, 0.f, 0.f, 0.f};

    // stage A (4 insts) + B (2 insts) for one KT into buffer BUF
    #define STAGE(BUF, KT) do {                                                               \
        _Pragma("unroll")                                                                     \
        for (int inst_ = 0; inst_ < 4; ++inst_) {                                             \
            const int q_ = inst_ * 256 + tid;                                                 \
            const int r_ = q_ >> 2;                                                           \
            const int c_ = (q_ & 3) ^ ((q_ >> 3) & 3);                                        \
            const unsigned short* src_ = Xb + (size_t)(Mbase + r_) * DIM + (KT) * BK + c_ * 8; \
            unsigned short* dst_ = &lds[BUF][(inst_ * 256 + wid * 64) * 8];                   \
            __builtin_amdgcn_global_load_lds((const __attribute__((address_space(1))) void*)src_, \
                                             (__attribute__((address_space(3))) void*)dst_, 16, 0, 0); \
        }                                                                                     \
        _Pragma("unroll")                                                                     \
        for (int inst_ = 0; inst_ < 2; ++inst_) {                                             \
            const int q_ = inst_ * 256 + tid;                                                 \
            const int r_ = q_ >> 2;                                                           \
            const int c_ = (q_ & 3) ^ ((q_ >> 3) & 3);                                        \
            const unsigned short* src_ = Xb + (size_t)(Nbase + r_) * DIM + (KT) * BK + c_ * 8; \
            unsigned short* dst_ = &lds[BUF][(1024 + inst_ * 256 + wid * 64) * 8];            \
            __builtin_amdgcn_global_load_lds((const __attribute__((address_space(1))) void*)src_, \
                                             (__attribute__((address_space(3))) void*)dst_, 16, 0, 0); \
        }                                                                                     \
    } while (0)

    STAGE(0, 0);
    __syncthreads();

    #pragma unroll 2
    for (int kt = 0; kt < NKT; ++kt) {
        const int b = kt & 1;
        if (kt + 1 < NKT) STAGE(b ^ 1, kt + 1);

        const unsigned short* Ab = &lds[b][0];
        const unsigned short* Bb = &lds[b][1024 * 8];
        short8 af[4], af2[4], bf[4];

        // half-phase 1: af rows 0..63 of this wave's half + all bf; 16 MFMA
        #pragma unroll
        for (int mt = 0; mt < 4; ++mt)
            af[mt] = *(const short8*)(Ab + (((wm * 128 + mt * 16 + l15) << 2) + cx) * 8);
        #pragma unroll
        for (int nt = 0; nt < 4; ++nt)
            bf[nt] = *(const short8*)(Bb + (((wn * 64 + nt * 16 + l15) << 2) + cx) * 8);

        __builtin_amdgcn_s_setprio(1);
        #pragma unroll
        for (int mt = 0; mt < 4; ++mt)
            #pragma unroll
            for (int nt = 0; nt < 4; ++nt)
                acc[mt][nt] = __builtin_amdgcn_mfma_f32_16x16x32_bf16(af[mt], bf[nt], acc[mt][nt], 0, 0, 0);
        __builtin_amdgcn_s_setprio(0);

        // half-phase 2: af rows 64..127; 16 MFMA (reads overlap phase-1 MFMAs via lgkmcnt)
        #pragma unroll
        for (int mt = 0; mt < 4; ++mt)
            af2[mt] = *(const short8*)(Ab + (((wm * 128 + 64 + mt * 16 + l15) << 2) + cx) * 8);

        __builtin_amdgcn_s_setprio(1);
        #pragma unroll
        for (int mt = 0; mt < 4; ++mt)
            #pragma unroll
            for (int nt = 0; nt < 4; ++nt)
                acc[4 + mt][nt] = __builtin_amdgcn_mfma_f32_16x16x32_bf16(af2[mt], bf[nt], acc[4 + mt][nt], 0, 0, 0);
        __builtin_amdgcn_s_setprio(0);

        __syncthreads();   // drains vmcnt+lgkmcnt; flips buffers
    }
    #undef STAGE

    // ---- epilogue. C/D layout: col = l15, row = lk*4 + reg.
    // acc[m][n]: row wm*128 + m*16, col wn*64 + n*16. Mask only i==j; both paths.
    float* scratchf = (float*)&lds[0][0];  // [0..511]: row (wn*256+lrow); [512..767]: col (wm*128+lcol)
    float cv[4];
    #pragma unroll
    for (int n = 0; n < 4; ++n)
        cv[n] = cj[Nbase + wn * 64 + n * 16 + l15];

    float vt[4];
    #pragma unroll
    for (int n = 0; n < 4; ++n) vt[n] = -__builtin_inff();

    #pragma unroll
    for (int m = 0; m < 8; ++m) {
        #pragma unroll
        for (int r = 0; r < 4; ++r) {
            const int lrow = wm * 128 + m * 16 + lk * 4 + r;
            const int grow = Mbase + lrow;
            const float ci = cj[grow];
            float rv = -__builtin_inff();
            #pragma unroll
            for (int n = 0; n < 4; ++n) {
                const float dot2 = 2.f * acc[m][n][r];
                const bool dg = (grow == Nbase + wn * 64 + n * 16 + l15);
                float vr = cv[n] - dot2;
                float vc = ci - dot2;
                if (dg) { vr = -__builtin_inff(); vc = -__builtin_inff(); }
                rv = fmaxf(rv, vr);
                vt[n] = fmaxf(vt[n], vc);
            }
            #pragma unroll
            for (int off = 8; off >= 1; off >>= 1)
                rv = fmaxf(rv, __shfl_xor(rv, off));
            if (l15 == 0) scratchf[wn * 256 + lrow] = rv;
        }
    }
    #pragma unroll
    for (int n = 0; n < 4; ++n) {
        vt[n] = fmaxf(vt[n], __shfl_xor(vt[n], 16));
        vt[n] = fmaxf(vt[n], __shfl_xor(vt[n], 32));
        if (lk == 0) scratchf[512 + wm * 128 + wn * 64 + n * 16 + l15] = vt[n];
    }
    __syncthreads();

    // row-path (256 rows) and col-path (128 cols)
    partmax[(size_t)bn * NROWS + Mbase + tid] = fmaxf(scratchf[tid], scratchf[256 + tid]);
    if (tid < BTN)
        partmax[(size_t)(64 + bm) * NROWS + Nbase + tid] = fmaxf(scratchf[512 + tid], scratchf[640 + tid]);
}

// ---------------- kernel 3: per-row finalize + block partial sums ----------------
// Row i (strip a = i>>8): row-path slots bn in [2a, 64); col-path slots 64+bm, bm in [0, a].
__global__ void finalize1_kernel(const float* __restrict__ partmax,
                                 const float* __restrict__ basei,
                                 const float* __restrict__ posd,
                                 const int* __restrict__ valid,
                                 float* __restrict__ partials)
{
    const int tid = threadIdx.x;
    const int a   = blockIdx.x;
    const int row = a * 256 + tid;
    float m = -__builtin_inff();
    for (int bn = 2 * a; bn < 64; ++bn)
        m = fmaxf(m, partmax[(size_t)bn * NROWS + row]);
    for (int bm2 = 0; bm2 <= a; ++bm2)
        m = fmaxf(m, partmax[(size_t)(64 + bm2) * NROWS + row]);
    const float d2 = m + basei[row];
    const float mn = sqrtf(fmaxf(d2, 0.f));
    float loss = fmaxf(posd[row] - mn + MARGIN, 0.f);
    float cnt = 1.f;
    if (!valid[row]) { loss = 0.f; cnt = 0.f; }
    #pragma unroll
    for (int off = 32; off >= 1; off >>= 1) {
        loss += __shfl_xor(loss, off);
        cnt  += __shfl_xor(cnt, off);
    }
    __shared__ float sl[4], sc[4];
    const int w = tid >> 6, lane = tid & 63;
    if (lane == 0) { sl[w] = loss; sc[w] = cnt; }
    __syncthreads();
    if (tid == 0) {
        partials[blockIdx.x * 2]     = sl[0] + sl[1] + sl[2] + sl[3];
        partials[blockIdx.x * 2 + 1] = sc[0] + sc[1] + sc[2] + sc[3];
    }
}

// ---------------- kernel 4: final scalar ----------------
__global__ void finalize2_kernel(const float* __restrict__ partials, float* __restrict__ out)
{
    const int tid = threadIdx.x;   // 64 threads
    float l = 0.f, c = 0.f;
    if (tid < 32) { l = partials[tid * 2]; c = partials[tid * 2 + 1]; }
    #pragma unroll
    for (int off = 32; off >= 1; off >>= 1) {
        l += __shfl_xor(l, off);
        c += __shfl_xor(c, off);
    }
    if (tid == 0) out[0] = l / c;
}

extern "C" void kernel_launch(void* const* d_in, const int* in_sizes, int n_in,
                              void* d_out, int out_size, void* d_ws, size_t ws_size,
                              hipStream_t stream)
{
    const float* X = (const float*)d_in[0];   // [8192,1024] f32
    const float* P = (const float*)d_in[1];   // [1024] f32
    float* out = (float*)d_out;
    char* ws = (char*)d_ws;

    unsigned short* Xb = (unsigned short*)ws;                                // 16 MB bf16
    size_t off = (size_t)NROWS * DIM * sizeof(unsigned short);
    float* cj    = (float*)(ws + off);  off += (size_t)NROWS * 4;
    float* basei = (float*)(ws + off);  off += (size_t)NROWS * 4;
    float* posd  = (float*)(ws + off);  off += (size_t)NROWS * 4;
    int*   valid = (int*)(ws + off);    off += (size_t)NROWS * 4;
    float* partmax = (float*)(ws + off); off += (size_t)96 * NROWS * 4;      // 3 MB
    float* partials = (float*)(ws + off);

    prep_kernel<<<NROWS / 4, 256, 0, stream>>>(X, P, Xb, cj, basei, posd, valid);
    gemm_max_kernel<<<NUNITS, 256, 0, stream>>>(Xb, cj, partmax);
    finalize1_kernel<<<NROWS / 256, 256, 0, stream>>>(partmax, basei, posd, valid, partials);
    finalize2_kernel<<<1, 64, 0, stream>>>(partials, out);
}